// Round 9
// baseline (360.255 us; speedup 1.0000x reference)
//
#include <hip/hip_runtime.h>

typedef _Float16 f16;
typedef __attribute__((ext_vector_type(8))) _Float16 half8;
typedef __attribute__((ext_vector_type(4))) _Float16 half4;
typedef __attribute__((ext_vector_type(2))) __fp16 fp16x2;
typedef __attribute__((ext_vector_type(4))) float f32x4;
typedef __attribute__((ext_vector_type(16))) float f32x16;

#define DEVINL __device__ __forceinline__

constexpr int NBATCH = 4, T = 2048, D = 1024, H = 16, DH = 64;
constexpr int M = NBATCH * T;                 // 8192 rows
constexpr float SCL2 = 0.18033688011f;        // (1/sqrt(64)) * log2(e), folded into Q at projection

// ---- async global->LDS 16B (linear dest: lds = wavebase + lane*16) ----
DEVINL void async16(const f16* g, f16* l) {
  __builtin_amdgcn_global_load_lds(
      (__attribute__((address_space(1))) void*)(g),
      (__attribute__((address_space(3))) void*)(l), 16, 0, 0);
}

DEVINL unsigned pk2(float x, float y) {
  auto h = __builtin_amdgcn_cvt_pkrtz(x, y);  // __fp16 ext_vector(2)
  return __builtin_bit_cast(unsigned, h);
}

DEVINL fp16x2 u2h(unsigned u) { return __builtin_bit_cast(fp16x2, u); }

union H8U {
  half8 h;
  unsigned u[4];
};

// ---- fused f32 -> f16 convert: query (2M float4) + 4 weights (256K float4 each)
// dst is contiguous: [Xh 8M halfs][Wh 4M halfs]
__global__ void cvt_all_kernel(const float* __restrict__ query,
                               const float* __restrict__ wq, const float* __restrict__ wk,
                               const float* __restrict__ wv, const float* __restrict__ wo,
                               f16* __restrict__ dst) {
  constexpr int NQ4 = M * D / 4;            // 2,097,152
  constexpr int NW4 = D * D / 4;            // 262,144
  constexpr int NT4 = NQ4 + 4 * NW4;
  const float* srcs[4] = {wq, wk, wv, wo};
  int i = blockIdx.x * blockDim.x + threadIdx.x;
  int stride = gridDim.x * blockDim.x;
  for (; i < NT4; i += stride) {
    const float* s;
    int off;
    if (i < NQ4) { s = query; off = i; }
    else {
      int j = i - NQ4;
      s = srcs[j >> 18];          // 2^18 == NW4
      off = j & (NW4 - 1);
    }
    float4 v = reinterpret_cast<const float4*>(s)[off];
    half4 h = {(f16)v.x, (f16)v.y, (f16)v.z, (f16)v.w};
    reinterpret_cast<half4*>(dst)[i] = h;
  }
}

// ---- shared GEMM body: C = (A @ W^T + bias) * oscale (m97 structure, 128x128, BK=32) ----
template<bool F32OUT>
DEVINL void gemm_body(const f16* __restrict__ A, const f16* __restrict__ W,
                      const float* __restrict__ bias, void* __restrict__ out,
                      f16* As, f16* Bs, long bm, long bn, float oscale) {
  constexpr int K = 1024, BK = 32, NCOL = 1024;
  const int tid = threadIdx.x;
  const int lane = tid & 63, wave = tid >> 6;
  const int wr = wave >> 1, wc = wave & 1;
  const int srow = tid >> 2, scol = (tid & 3) * 8;
  const f16* gA = A + (bm + srow) * (long)K + scol;
  const f16* gB = W + (bn + srow) * (long)K + scol;
  f16* lA = &As[srow * BK + scol];
  f16* lB = &Bs[srow * BK + scol];
  const int fr = lane & 15, fk = (lane >> 4) * 8;
  f32x4 acc[4][4] = {};

  for (int k0 = 0; k0 < K; k0 += BK) {
    async16(gA + k0, lA);
    async16(gA + k0 + 64 * K, lA + 64 * BK);
    async16(gB + k0, lB);
    async16(gB + k0 + 64 * K, lB + 64 * BK);
    __syncthreads();
    half8 af[4], bf[4];
#pragma unroll
    for (int m = 0; m < 4; ++m)
      af[m] = *(const half8*)&As[(wr * 64 + m * 16 + fr) * BK + fk];
#pragma unroll
    for (int n = 0; n < 4; ++n)
      bf[n] = *(const half8*)&Bs[(wc * 64 + n * 16 + fr) * BK + fk];
#pragma unroll
    for (int m = 0; m < 4; ++m)
#pragma unroll
      for (int n = 0; n < 4; ++n)
        acc[m][n] = __builtin_amdgcn_mfma_f32_16x16x32_f16(af[m], bf[n], acc[m][n], 0, 0, 0);
    __syncthreads();
  }
  const int rq = (lane >> 4) * 4;
#pragma unroll
  for (int m = 0; m < 4; ++m) {
    const long row = bm + wr * 64 + m * 16 + rq;
#pragma unroll
    for (int n = 0; n < 4; ++n) {
      const long col = bn + wc * 64 + n * 16 + fr;
      const float bb = bias[col];
#pragma unroll
      for (int r = 0; r < 4; ++r) {
        float v = (acc[m][n][r] + bb) * oscale;
        if (F32OUT) ((float*)out)[(row + r) * (long)NCOL + col] = v;
        else        ((f16*)out)[(row + r) * (long)NCOL + col] = (f16)v;
      }
    }
  }
}

// fused QKV: grid (8, 64, 3).  Q output is pre-scaled by SCL2 (softmax scale folded in).
__global__ __launch_bounds__(256) void gemm_qkv(const f16* __restrict__ A,
                                                const f16* __restrict__ Wall,
                                                const float* __restrict__ bq,
                                                const float* __restrict__ bk,
                                                const float* __restrict__ bv,
                                                f16* __restrict__ Qh,
                                                f16* __restrict__ Kh,
                                                f16* __restrict__ Vh) {
  __shared__ __align__(16) f16 As[128 * 32];
  __shared__ __align__(16) f16 Bs[128 * 32];
  const int z = blockIdx.z;
  const f16* W = Wall + (size_t)z * D * D;
  const float* bias = z == 0 ? bq : (z == 1 ? bk : bv);
  f16* out = z == 0 ? Qh : (z == 1 ? Kh : Vh);
  const float oscale = z == 0 ? SCL2 : 1.0f;
  gemm_body<false>(A, W, bias, (void*)out, As, Bs,
                   (long)blockIdx.y * 128, (long)blockIdx.x * 128, oscale);
}

__global__ __launch_bounds__(256) void gemm_out(const f16* __restrict__ A,
                                                const f16* __restrict__ W,
                                                const float* __restrict__ bias,
                                                float* __restrict__ out) {
  __shared__ __align__(16) f16 As[128 * 32];
  __shared__ __align__(16) f16 Bs[128 * 32];
  gemm_body<true>(A, W, bias, (void*)out, As, Bs,
                  (long)blockIdx.y * 128, (long)blockIdx.x * 128, 1.0f);
}

// ---- flash attention, swapped-QK^T 32x32, max-free softmax, 1-iter software pipeline ----
// iter t: QK(t) || PV(t-1); exp/pack(t) has a full iteration of slack (consumed by PV(t)
// at iter t+1).  One barrier per iter; K staged 2 ahead (post-barrier, into the buffer
// whose reads completed pre-barrier); V global-loaded 2 ahead into 2 reg slots,
// ds-written 1 ahead post-barrier.
__global__ __launch_bounds__(256, 4) void attn_kernel(const f16* __restrict__ Qh,
                                                      const f16* __restrict__ Kh,
                                                      const f16* __restrict__ Vh,
                                                      const int* __restrict__ mask,
                                                      f16* __restrict__ Ch) {
  constexpr int NT = T / 64;
  constexpr int LDV = 72;  // V^T row stride in halfs (144B): measured-cheap LDS pattern
  __shared__ __align__(16) f16 smem[17408];
  f16* Ksb0 = smem;
  f16* Ksb1 = smem + 4096;
  f16* Vtb0 = smem + 8192;
  f16* Vtb1 = smem + 8192 + 4608;

  const int nh = blockIdx.y;
  const int bn = nh >> 4;
  const int bh = nh & 15;
  const int qt0 = blockIdx.x * 128;
  const int tid = threadIdx.x, lane = tid & 63, wave = tid >> 6;
  const int q = lane & 31, hi = lane >> 5;

  const long base = ((long)bn * T) * D + (long)bh * DH;
  const int qrow = qt0 + wave * 32 + q;

  // Q fragments (persistent, pre-scaled): zeroed if this query row is masked
  // (s == 0 -> p == 1 uniform -> O = mean(V), exactly the reference's masked softmax)
  const bool pm = mask[bn * T + qrow] != 0;
  half8 qf[4];
#pragma unroll
  for (int f = 0; f < 4; ++f) {
    qf[f] = *(const half8*)&Qh[base + (long)qrow * D + f * 16 + hi * 8];
    if (!pm) qf[f] = half8{};
  }

  f32x16 o0 = {}, o1 = {};
  float lsum = 0.0f;
  const fp16x2 one2 = {(__fp16)1.0f, (__fp16)1.0f};

  // --- K staging: chunk-XOR swizzled source, linear LDS dest ---
  const int skey = tid >> 3;
  const int sc = tid & 7;
  const int kcol = ((sc ^ (skey & 7)) * 8);
  const f16* ksrc0 = Kh + base + (long)skey * D + kcol;
  const f16* ksrc1 = Kh + base + (long)(skey + 32) * D + kcol;

  // --- V staging: row s = lane, d-cols wave*16 .. +16 ---
  const int vs = lane;
  const int vd = wave * 16;
  const f16* vsrc = Vh + base + (long)vs * D + vd;

  // prologue: K(0)->Ksb0, K(1)->Ksb1 (async); V(0)->Vtb0 (via regs); V(1)->slot B
  async16(ksrc0, Ksb0 + tid * 8);
  async16(ksrc1, Ksb0 + 2048 + tid * 8);
  async16(ksrc0 + 64 * D, Ksb1 + tid * 8);
  async16(ksrc1 + 64 * D, Ksb1 + 2048 + tid * 8);
  half8 vA0 = *(const half8*)(vsrc);
  half8 vA1 = *(const half8*)(vsrc + 8);
  half8 vB0 = *(const half8*)(vsrc + 64 * D);
  half8 vB1 = *(const half8*)(vsrc + 64 * D + 8);
  {
#pragma unroll
    for (int j = 0; j < 8; ++j) Vtb0[(vd + j) * LDV + vs] = vA0[j];
#pragma unroll
    for (int j = 0; j < 8; ++j) Vtb0[(vd + 8 + j) * LDV + vs] = vA1[j];
  }
  __syncthreads();

  half8 pfA[4], pfB[4];

  // Body: iter T_: QK(T_) from KB; PV(T_-1) from VP with PFC; exp/pack -> PFN;
  // barrier; stage K(T_+2)->KB; write V(T_+1) (regs W0/W1) -> VP; load V(T_+2)->L0/L1.
#define ATTN_BODY(T_, PFC, PFN, KB, VP, W0, W1, L0, L1)                         \
  {                                                                             \
    const int t_ = (T_);                                                        \
    f32x16 s0 = {}, s1 = {};                                                    \
    __builtin_amdgcn_s_setprio(1);                                              \
    _Pragma("unroll")                                                           \
    for (int f = 0; f < 4; ++f) {                                               \
      const int ck = f * 2 + hi;                                                \
      half8 k0 = *(const half8*)&KB[q * 64 + ((ck ^ (q & 7)) * 8)];             \
      half8 k1 = *(const half8*)&KB[(32 + q) * 64 + ((ck ^ (q & 7)) * 8)];      \
      s0 = __builtin_amdgcn_mfma_f32_32x32x16_f16(k0, qf[f], s0, 0, 0, 0);      \
      s1 = __builtin_amdgcn_mfma_f32_32x32x16_f16(k1, qf[f], s1, 0, 0, 0);      \
    }                                                                           \
    if (t_ > 0) {                                                               \
      _Pragma("unroll")                                                         \
      for (int kc = 0; kc < 4; ++kc) {                                          \
        half8 v0f = *(const half8*)&VP[q * LDV + kc * 16 + hi * 8];             \
        half8 v1f = *(const half8*)&VP[(32 + q) * LDV + kc * 16 + hi * 8];      \
        o0 = __builtin_amdgcn_mfma_f32_32x32x16_f16(v0f, PFC[kc], o0, 0, 0, 0); \
        o1 = __builtin_amdgcn_mfma_f32_32x32x16_f16(v1f, PFC[kc], o1, 0, 0, 0); \
      }                                                                         \
    }                                                                           \
    __builtin_amdgcn_s_setprio(0);                                              \
    _Pragma("unroll")                                                           \
    for (int r = 0; r < 16; ++r) {                                              \
      s0[r] = __builtin_amdgcn_exp2f(s0[r]);                                    \
      s1[r] = __builtin_amdgcn_exp2f(s1[r]);                                    \
    }                                                                           \
    _Pragma("unroll")                                                           \
    for (int g = 0; g < 4; ++g) {                                               \
      float p0, p1, p2, p3, p4, p5, p6, p7;                                     \
      if (g == 0) { p0=s0[0];p1=s0[1];p2=s0[2];p3=s0[3];p4=s0[4];p5=s0[5];p6=s0[6];p7=s0[7]; } \
      else if (g == 1) { p0=s0[8];p1=s0[9];p2=s0[10];p3=s0[11];p4=s0[12];p5=s0[13];p6=s0[14];p7=s0[15]; } \
      else if (g == 2) { p0=s1[0];p1=s1[1];p2=s1[2];p3=s1[3];p4=s1[4];p5=s1[5];p6=s1[6];p7=s1[7]; } \
      else { p0=s1[8];p1=s1[9];p2=s1[10];p3=s1[11];p4=s1[12];p5=s1[13];p6=s1[14];p7=s1[15]; } \
      unsigned A0 = pk2(p0, p1), A1 = pk2(p2, p3);                              \
      unsigned B0 = pk2(p4, p5), B1 = pk2(p6, p7);                              \
      float sgs = __builtin_amdgcn_fdot2(u2h(A0), one2, 0.0f, false);           \
      sgs = __builtin_amdgcn_fdot2(u2h(A1), one2, sgs, false);                  \
      sgs = __builtin_amdgcn_fdot2(u2h(B0), one2, sgs, false);                  \
      sgs = __builtin_amdgcn_fdot2(u2h(B1), one2, sgs, false);                  \
      lsum += sgs;                                                              \
      asm("v_permlane32_swap_b32 %0, %1" : "+v"(A0), "+v"(B0));                 \
      asm("v_permlane32_swap_b32 %0, %1" : "+v"(A1), "+v"(B1));                 \
      H8U u;                                                                    \
      u.u[0] = A0; u.u[1] = A1; u.u[2] = B0; u.u[3] = B1;                       \
      PFN[g] = u.h;                                                             \
    }                                                                           \
    __syncthreads();                                                            \
    if (t_ + 2 < NT) {                                                          \
      const long koff = (long)(t_ + 2) * 64 * D;                                \
      async16(ksrc0 + koff, KB + tid * 8);                                      \
      async16(ksrc1 + koff, KB + 2048 + tid * 8);                               \
    }                                                                           \
    if (t_ + 1 < NT) {                                                          \
      _Pragma("unroll")                                                         \
      for (int j = 0; j < 8; ++j) VP[(vd + j) * LDV + vs] = W0[j];              \
      _Pragma("unroll")                                                         \
      for (int j = 0; j < 8; ++j) VP[(vd + 8 + j) * LDV + vs] = W1[j];          \
    }                                                                           \
    if (t_ + 2 < NT) {                                                          \
      const long koff2 = (long)(t_ + 2) * 64 * D;                               \
      L0 = *(const half8*)(vsrc + koff2);                                       \
      L1 = *(const half8*)(vsrc + koff2 + 8);                                   \
    }                                                                           \
  }

  for (int t2 = 0; t2 < NT; t2 += 2) {
    // even iter: K in Ksb0; PV(t-1) reads Vtb1; write V(t+1)->Vtb1 from slot B; load->slot A
    ATTN_BODY(t2, pfA, pfB, Ksb0, Vtb1, vB0, vB1, vA0, vA1)
    // odd iter: K in Ksb1; PV(t-1) reads Vtb0; write V(t+1)->Vtb0 from slot A; load->slot B
    ATTN_BODY(t2 + 1, pfB, pfA, Ksb1, Vtb0, vA0, vA1, vB0, vB1)
  }
#undef ATTN_BODY

  // final PV(NT-1): pf = pfA (last iter's PFN), V in Vtb1 ((NT-1)&1 == 1)
  {
    __builtin_amdgcn_s_setprio(1);
#pragma unroll
    for (int kc = 0; kc < 4; ++kc) {
      half8 v0f = *(const half8*)&Vtb1[q * LDV + kc * 16 + hi * 8];
      half8 v1f = *(const half8*)&Vtb1[(32 + q) * LDV + kc * 16 + hi * 8];
      o0 = __builtin_amdgcn_mfma_f32_32x32x16_f16(v0f, pfA[kc], o0, 0, 0, 0);
      o1 = __builtin_amdgcn_mfma_f32_32x32x16_f16(v1f, pfA[kc], o1, 0, 0, 0);
    }
    __builtin_amdgcn_s_setprio(0);
  }
  __syncthreads();  // all waves done with K/V LDS before epilogue reuses it

  // ---- epilogue: lrow across hi halves; O/l -> LDS transpose -> coalesced stores ----
  float lrow = lsum + __shfl_xor(lsum, 32);
  constexpr int EPL = 72;
  const float rl = 1.0f / lrow;
  f16* ep = smem + wave * 2304;  // 32 rows x 72 halfs per wave (reuses staging LDS)
#pragma unroll
  for (int r = 0; r < 16; r += 2) {
    const int dd = (r & 3) + 8 * (r >> 2) + 4 * hi;
    *(unsigned*)&ep[q * EPL + dd]      = pk2(o0[r] * rl, o0[r + 1] * rl);
    *(unsigned*)&ep[q * EPL + 32 + dd] = pk2(o1[r] * rl, o1[r + 1] * rl);
  }
  asm volatile("s_waitcnt lgkmcnt(0)" ::: "memory");
  const int rr = lane >> 1, cw = lane & 1;
  const long orow = base + (long)(qt0 + wave * 32 + rr) * D + cw * 32;
#pragma unroll
  for (int c2 = 0; c2 < 4; ++c2) {
    half8 val = *(const half8*)&ep[rr * EPL + cw * 32 + c2 * 8];
    *(half8*)&Ch[orow + c2 * 8] = val;
  }
}

extern "C" void kernel_launch(void* const* d_in, const int* in_sizes, int n_in,
                              void* d_out, int out_size, void* d_ws, size_t ws_size,
                              hipStream_t stream) {
  const float* query = (const float*)d_in[0];
  const int*   mask  = (const int*)d_in[1];
  const float* Wq = (const float*)d_in[2];
  const float* bq = (const float*)d_in[3];
  const float* Wk = (const float*)d_in[4];
  const float* bk = (const float*)d_in[5];
  const float* Wv = (const float*)d_in[6];
  const float* bv = (const float*)d_in[7];
  const float* Wo = (const float*)d_in[8];
  const float* bo = (const float*)d_in[9];

  char* ws = (char*)d_ws;
  const size_t MD = (size_t)M * D;
  f16* Xh = (f16*)ws;                              // 16 MB (reused as Ch after QKV)
  f16* Wh = (f16*)(ws + (16u << 20));              // 8 MB: Wq,Wk,Wv,Wo f16 (contiguous after Xh)
  f16* Qh = (f16*)(ws + (24u << 20));              // 16 MB
  f16 *KhP, *VhP;
  const size_t need = (24u << 20) + 3 * MD * sizeof(f16);
  if (ws_size >= need) {
    KhP = Qh + MD; VhP = KhP + MD;
  } else {
    KhP = (f16*)d_out; VhP = KhP + MD;
  }
  f16* Ch = Xh;

  cvt_all_kernel<<<dim3(2048), dim3(256), 0, stream>>>(query, Wq, Wk, Wv, Wo, Xh);

  gemm_qkv<<<dim3(8, 64, 3), dim3(256), 0, stream>>>(Xh, Wh, bq, bk, bv, Qh, KhP, VhP);

  attn_kernel<<<dim3(T / 128, NBATCH * H), dim3(256), 0, stream>>>(Qh, KhP, VhP, mask, Ch);

  gemm_out<<<dim3(8, 64), dim3(256), 0, stream>>>(Ch, Wh + 3 * (size_t)D * D, bo, (float*)d_out);
}

// Round 10
// 313.957 us; speedup vs baseline: 1.1475x; 1.1475x over previous
//
#include <hip/hip_runtime.h>

typedef _Float16 f16;
typedef __attribute__((ext_vector_type(8))) _Float16 half8;
typedef __attribute__((ext_vector_type(4))) _Float16 half4;
typedef __attribute__((ext_vector_type(2))) __fp16 fp16x2;
typedef __attribute__((ext_vector_type(4))) float f32x4;
typedef __attribute__((ext_vector_type(16))) float f32x16;

#define DEVINL __device__ __forceinline__

constexpr int NBATCH = 4, T = 2048, D = 1024, H = 16, DH = 64;
constexpr int M = NBATCH * T;                 // 8192 rows
constexpr float SCL2 = 0.18033688011f;        // (1/sqrt(64)) * log2(e), folded into Q at projection

// ---- async global->LDS 16B (linear dest: lds = wavebase + lane*16) ----
DEVINL void async16(const f16* g, f16* l) {
  __builtin_amdgcn_global_load_lds(
      (__attribute__((address_space(1))) void*)(g),
      (__attribute__((address_space(3))) void*)(l), 16, 0, 0);
}

DEVINL unsigned pk2(float x, float y) {
  auto h = __builtin_amdgcn_cvt_pkrtz(x, y);  // __fp16 ext_vector(2)
  return __builtin_bit_cast(unsigned, h);
}

DEVINL fp16x2 u2h(unsigned u) { return __builtin_bit_cast(fp16x2, u); }

union H8U {
  half8 h;
  unsigned u[4];
};

// ---- fused f32 -> f16 convert: query (2M float4) + 4 weights (256K float4 each)
// dst is contiguous: [Xh 8M halfs][Wh 4M halfs]
__global__ void cvt_all_kernel(const float* __restrict__ query,
                               const float* __restrict__ wq, const float* __restrict__ wk,
                               const float* __restrict__ wv, const float* __restrict__ wo,
                               f16* __restrict__ dst) {
  constexpr int NQ4 = M * D / 4;            // 2,097,152
  constexpr int NW4 = D * D / 4;            // 262,144
  constexpr int NT4 = NQ4 + 4 * NW4;
  const float* srcs[4] = {wq, wk, wv, wo};
  int i = blockIdx.x * blockDim.x + threadIdx.x;
  int stride = gridDim.x * blockDim.x;
  for (; i < NT4; i += stride) {
    const float* s;
    int off;
    if (i < NQ4) { s = query; off = i; }
    else {
      int j = i - NQ4;
      s = srcs[j >> 18];          // 2^18 == NW4
      off = j & (NW4 - 1);
    }
    float4 v = reinterpret_cast<const float4*>(s)[off];
    half4 h = {(f16)v.x, (f16)v.y, (f16)v.z, (f16)v.w};
    reinterpret_cast<half4*>(dst)[i] = h;
  }
}

// ---- shared GEMM body: C = (A @ W^T + bias) * oscale (m97 structure, 128x128, BK=32) ----
template<bool F32OUT>
DEVINL void gemm_body(const f16* __restrict__ A, const f16* __restrict__ W,
                      const float* __restrict__ bias, void* __restrict__ out,
                      f16* As, f16* Bs, long bm, long bn, float oscale) {
  constexpr int K = 1024, BK = 32, NCOL = 1024;
  const int tid = threadIdx.x;
  const int lane = tid & 63, wave = tid >> 6;
  const int wr = wave >> 1, wc = wave & 1;
  const int srow = tid >> 2, scol = (tid & 3) * 8;
  const f16* gA = A + (bm + srow) * (long)K + scol;
  const f16* gB = W + (bn + srow) * (long)K + scol;
  f16* lA = &As[srow * BK + scol];
  f16* lB = &Bs[srow * BK + scol];
  const int fr = lane & 15, fk = (lane >> 4) * 8;
  f32x4 acc[4][4] = {};

  for (int k0 = 0; k0 < K; k0 += BK) {
    async16(gA + k0, lA);
    async16(gA + k0 + 64 * K, lA + 64 * BK);
    async16(gB + k0, lB);
    async16(gB + k0 + 64 * K, lB + 64 * BK);
    __syncthreads();
    half8 af[4], bf[4];
#pragma unroll
    for (int m = 0; m < 4; ++m)
      af[m] = *(const half8*)&As[(wr * 64 + m * 16 + fr) * BK + fk];
#pragma unroll
    for (int n = 0; n < 4; ++n)
      bf[n] = *(const half8*)&Bs[(wc * 64 + n * 16 + fr) * BK + fk];
#pragma unroll
    for (int m = 0; m < 4; ++m)
#pragma unroll
      for (int n = 0; n < 4; ++n)
        acc[m][n] = __builtin_amdgcn_mfma_f32_16x16x32_f16(af[m], bf[n], acc[m][n], 0, 0, 0);
    __syncthreads();
  }
  const int rq = (lane >> 4) * 4;
#pragma unroll
  for (int m = 0; m < 4; ++m) {
    const long row = bm + wr * 64 + m * 16 + rq;
#pragma unroll
    for (int n = 0; n < 4; ++n) {
      const long col = bn + wc * 64 + n * 16 + fr;
      const float bb = bias[col];
#pragma unroll
      for (int r = 0; r < 4; ++r) {
        float v = (acc[m][n][r] + bb) * oscale;
        if (F32OUT) ((float*)out)[(row + r) * (long)NCOL + col] = v;
        else        ((f16*)out)[(row + r) * (long)NCOL + col] = (f16)v;
      }
    }
  }
}

// fused QKV: grid (8, 64, 3).  Q output is pre-scaled by SCL2 (softmax scale folded in).
__global__ __launch_bounds__(256) void gemm_qkv(const f16* __restrict__ A,
                                                const f16* __restrict__ Wall,
                                                const float* __restrict__ bq,
                                                const float* __restrict__ bk,
                                                const float* __restrict__ bv,
                                                f16* __restrict__ Qh,
                                                f16* __restrict__ Kh,
                                                f16* __restrict__ Vh) {
  __shared__ __align__(16) f16 As[128 * 32];
  __shared__ __align__(16) f16 Bs[128 * 32];
  const int z = blockIdx.z;
  const f16* W = Wall + (size_t)z * D * D;
  const float* bias = z == 0 ? bq : (z == 1 ? bk : bv);
  f16* out = z == 0 ? Qh : (z == 1 ? Kh : Vh);
  const float oscale = z == 0 ? SCL2 : 1.0f;
  gemm_body<false>(A, W, bias, (void*)out, As, Bs,
                   (long)blockIdx.y * 128, (long)blockIdx.x * 128, oscale);
}

__global__ __launch_bounds__(256) void gemm_out(const f16* __restrict__ A,
                                                const f16* __restrict__ W,
                                                const float* __restrict__ bias,
                                                float* __restrict__ out) {
  __shared__ __align__(16) f16 As[128 * 32];
  __shared__ __align__(16) f16 Bs[128 * 32];
  gemm_body<true>(A, W, bias, (void*)out, As, Bs,
                  (long)blockIdx.y * 128, (long)blockIdx.x * 128, 1.0f);
}

// ---- flash attention, swapped-QK^T 32x32, max-free softmax, 1-iter skew (lean regs) ----
// iter t: issue QK(t) MFMAs, then PV(t-1) MFMAs (uses pf packed at t-1), THEN exp/pack(t)
// overwrites pf (WAR after PV consumed it).  While the wave waits on QK accumulators for
// exp, the 8 PV MFMAs fill the pipe.  Single pf[4], single V reg slot -> ~120 VGPR peak.
__global__ __launch_bounds__(256, 4) void attn_kernel(const f16* __restrict__ Qh,
                                                      const f16* __restrict__ Kh,
                                                      const f16* __restrict__ Vh,
                                                      const int* __restrict__ mask,
                                                      f16* __restrict__ Ch) {
  constexpr int NT = T / 64;
  constexpr int LDV = 72;  // V^T row stride in halfs (144B): measured-cheap LDS pattern
  __shared__ __align__(16) f16 smem[17408];
  f16* Ksb0 = smem;
  f16* Ksb1 = smem + 4096;
  f16* Vtb0 = smem + 8192;
  f16* Vtb1 = smem + 8192 + 4608;

  const int nh = blockIdx.y;
  const int bn = nh >> 4;
  const int bh = nh & 15;
  const int qt0 = blockIdx.x * 128;
  const int tid = threadIdx.x, lane = tid & 63, wave = tid >> 6;
  const int q = lane & 31, hi = lane >> 5;

  const long base = ((long)bn * T) * D + (long)bh * DH;
  const int qrow = qt0 + wave * 32 + q;

  // Q fragments (persistent, pre-scaled): zeroed if this query row is masked
  // (s == 0 -> p == 1 uniform -> O = mean(V), exactly the reference's masked softmax)
  const bool pm = mask[bn * T + qrow] != 0;
  half8 qf[4];
#pragma unroll
  for (int f = 0; f < 4; ++f) {
    qf[f] = *(const half8*)&Qh[base + (long)qrow * D + f * 16 + hi * 8];
    if (!pm) qf[f] = half8{};
  }

  f32x16 o0 = {}, o1 = {};
  float lsum = 0.0f;
  const fp16x2 one2 = {(__fp16)1.0f, (__fp16)1.0f};

  // --- K staging: chunk-XOR swizzled source, linear LDS dest ---
  const int skey = tid >> 3;
  const int sc = tid & 7;
  const int kcol = ((sc ^ (skey & 7)) * 8);
  const f16* ksrc0 = Kh + base + (long)skey * D + kcol;
  const f16* ksrc1 = Kh + base + (long)(skey + 32) * D + kcol;

  // --- V staging: row s = lane, d-cols wave*16 .. +16 ---
  const int vs = lane;
  const int vd = wave * 16;
  const f16* vsrc = Vh + base + (long)vs * D + vd;

  // prologue: K(0)->Ksb0, K(1)->Ksb1 (async); V(0)->Vtb0 via regs; then V(1)->va/vb
  async16(ksrc0, Ksb0 + tid * 8);
  async16(ksrc1, Ksb0 + 2048 + tid * 8);
  async16(ksrc0 + 64 * D, Ksb1 + tid * 8);
  async16(ksrc1 + 64 * D, Ksb1 + 2048 + tid * 8);
  half8 va = *(const half8*)(vsrc);
  half8 vb = *(const half8*)(vsrc + 8);
  {
#pragma unroll
    for (int j = 0; j < 8; ++j) Vtb0[(vd + j) * LDV + vs] = va[j];
#pragma unroll
    for (int j = 0; j < 8; ++j) Vtb0[(vd + 8 + j) * LDV + vs] = vb[j];
  }
  va = *(const half8*)(vsrc + 64 * D);
  vb = *(const half8*)(vsrc + 64 * D + 8);
  __syncthreads();

  half8 pf[4];

  // Body iter T_: QK(T_) from KB; PV(T_-1) from VP (pf from T_-1); exp/pack -> pf;
  // barrier; stage K(T_+2)->KB (just-read buffer); write V(T_+1) (va/vb) -> VP
  // (just-read buffer: (T_-1)&1 == (T_+1)&1); load V(T_+2) -> va/vb.
#define ATTN_BODY(T_, KB, VP)                                                   \
  {                                                                             \
    const int t_ = (T_);                                                        \
    f32x16 s0 = {}, s1 = {};                                                    \
    __builtin_amdgcn_s_setprio(1);                                              \
    _Pragma("unroll")                                                           \
    for (int f = 0; f < 4; ++f) {                                               \
      const int ck = f * 2 + hi;                                                \
      half8 k0 = *(const half8*)&KB[q * 64 + ((ck ^ (q & 7)) * 8)];             \
      half8 k1 = *(const half8*)&KB[(32 + q) * 64 + ((ck ^ (q & 7)) * 8)];      \
      s0 = __builtin_amdgcn_mfma_f32_32x32x16_f16(k0, qf[f], s0, 0, 0, 0);      \
      s1 = __builtin_amdgcn_mfma_f32_32x32x16_f16(k1, qf[f], s1, 0, 0, 0);      \
    }                                                                           \
    if (t_ > 0) {                                                               \
      _Pragma("unroll")                                                         \
      for (int kc = 0; kc < 4; ++kc) {                                          \
        half8 v0f = *(const half8*)&VP[q * LDV + kc * 16 + hi * 8];             \
        half8 v1f = *(const half8*)&VP[(32 + q) * LDV + kc * 16 + hi * 8];      \
        o0 = __builtin_amdgcn_mfma_f32_32x32x16_f16(v0f, pf[kc], o0, 0, 0, 0);  \
        o1 = __builtin_amdgcn_mfma_f32_32x32x16_f16(v1f, pf[kc], o1, 0, 0, 0);  \
      }                                                                         \
    }                                                                           \
    __builtin_amdgcn_s_setprio(0);                                              \
    _Pragma("unroll")                                                           \
    for (int r = 0; r < 16; ++r) {                                              \
      s0[r] = __builtin_amdgcn_exp2f(s0[r]);                                    \
      s1[r] = __builtin_amdgcn_exp2f(s1[r]);                                    \
    }                                                                           \
    _Pragma("unroll")                                                           \
    for (int g = 0; g < 4; ++g) {                                               \
      float p0, p1, p2, p3, p4, p5, p6, p7;                                     \
      if (g == 0) { p0=s0[0];p1=s0[1];p2=s0[2];p3=s0[3];p4=s0[4];p5=s0[5];p6=s0[6];p7=s0[7]; } \
      else if (g == 1) { p0=s0[8];p1=s0[9];p2=s0[10];p3=s0[11];p4=s0[12];p5=s0[13];p6=s0[14];p7=s0[15]; } \
      else if (g == 2) { p0=s1[0];p1=s1[1];p2=s1[2];p3=s1[3];p4=s1[4];p5=s1[5];p6=s1[6];p7=s1[7]; } \
      else { p0=s1[8];p1=s1[9];p2=s1[10];p3=s1[11];p4=s1[12];p5=s1[13];p6=s1[14];p7=s1[15]; } \
      unsigned A0 = pk2(p0, p1), A1 = pk2(p2, p3);                              \
      unsigned B0 = pk2(p4, p5), B1 = pk2(p6, p7);                              \
      float sgs = __builtin_amdgcn_fdot2(u2h(A0), one2, 0.0f, false);           \
      sgs = __builtin_amdgcn_fdot2(u2h(A1), one2, sgs, false);                  \
      sgs = __builtin_amdgcn_fdot2(u2h(B0), one2, sgs, false);                  \
      sgs = __builtin_amdgcn_fdot2(u2h(B1), one2, sgs, false);                  \
      lsum += sgs;                                                              \
      asm("v_permlane32_swap_b32 %0, %1" : "+v"(A0), "+v"(B0));                 \
      asm("v_permlane32_swap_b32 %0, %1" : "+v"(A1), "+v"(B1));                 \
      H8U u;                                                                    \
      u.u[0] = A0; u.u[1] = A1; u.u[2] = B0; u.u[3] = B1;                       \
      pf[g] = u.h;                                                              \
    }                                                                           \
    __syncthreads();                                                            \
    if (t_ + 2 < NT) {                                                          \
      const long koff = (long)(t_ + 2) * 64 * D;                                \
      async16(ksrc0 + koff, KB + tid * 8);                                      \
      async16(ksrc1 + koff, KB + 2048 + tid * 8);                               \
    }                                                                           \
    if (t_ + 1 < NT) {                                                          \
      _Pragma("unroll")                                                         \
      for (int j = 0; j < 8; ++j) VP[(vd + j) * LDV + vs] = va[j];              \
      _Pragma("unroll")                                                         \
      for (int j = 0; j < 8; ++j) VP[(vd + 8 + j) * LDV + vs] = vb[j];          \
    }                                                                           \
    if (t_ + 2 < NT) {                                                          \
      const long koff2 = (long)(t_ + 2) * 64 * D;                               \
      va = *(const half8*)(vsrc + koff2);                                       \
      vb = *(const half8*)(vsrc + koff2 + 8);                                   \
    }                                                                           \
  }

  for (int t2 = 0; t2 < NT; t2 += 2) {
    // even t: K in Ksb0; PV(t-1) reads Vtb1; V(t+1) write -> Vtb1
    ATTN_BODY(t2, Ksb0, Vtb1)
    // odd t: K in Ksb1; PV(t-1) reads Vtb0; V(t+1) write -> Vtb0
    ATTN_BODY(t2 + 1, Ksb1, Vtb0)
  }
#undef ATTN_BODY

  // final PV(NT-1): pf from iter NT-1, V(NT-1) in Vtb1 ((NT-1)&1 == 1)
  {
    __builtin_amdgcn_s_setprio(1);
#pragma unroll
    for (int kc = 0; kc < 4; ++kc) {
      half8 v0f = *(const half8*)&Vtb1[q * LDV + kc * 16 + hi * 8];
      half8 v1f = *(const half8*)&Vtb1[(32 + q) * LDV + kc * 16 + hi * 8];
      o0 = __builtin_amdgcn_mfma_f32_32x32x16_f16(v0f, pf[kc], o0, 0, 0, 0);
      o1 = __builtin_amdgcn_mfma_f32_32x32x16_f16(v1f, pf[kc], o1, 0, 0, 0);
    }
    __builtin_amdgcn_s_setprio(0);
  }
  __syncthreads();  // all waves done with K/V LDS before epilogue reuses it

  // ---- epilogue: lrow across hi halves; O/l -> LDS transpose -> coalesced stores ----
  float lrow = lsum + __shfl_xor(lsum, 32);
  constexpr int EPL = 72;
  const float rl = 1.0f / lrow;
  f16* ep = smem + wave * 2304;  // 32 rows x 72 halfs per wave (reuses staging LDS)
#pragma unroll
  for (int r = 0; r < 16; r += 2) {
    const int dd = (r & 3) + 8 * (r >> 2) + 4 * hi;
    *(unsigned*)&ep[q * EPL + dd]      = pk2(o0[r] * rl, o0[r + 1] * rl);
    *(unsigned*)&ep[q * EPL + 32 + dd] = pk2(o1[r] * rl, o1[r + 1] * rl);
  }
  asm volatile("s_waitcnt lgkmcnt(0)" ::: "memory");
  const int rr = lane >> 1, cw = lane & 1;
  const long orow = base + (long)(qt0 + wave * 32 + rr) * D + cw * 32;
#pragma unroll
  for (int c2 = 0; c2 < 4; ++c2) {
    half8 val = *(const half8*)&ep[rr * EPL + cw * 32 + c2 * 8];
    *(half8*)&Ch[orow + c2 * 8] = val;
  }
}

extern "C" void kernel_launch(void* const* d_in, const int* in_sizes, int n_in,
                              void* d_out, int out_size, void* d_ws, size_t ws_size,
                              hipStream_t stream) {
  const float* query = (const float*)d_in[0];
  const int*   mask  = (const int*)d_in[1];
  const float* Wq = (const float*)d_in[2];
  const float* bq = (const float*)d_in[3];
  const float* Wk = (const float*)d_in[4];
  const float* bk = (const float*)d_in[5];
  const float* Wv = (const float*)d_in[6];
  const float* bv = (const float*)d_in[7];
  const float* Wo = (const float*)d_in[8];
  const float* bo = (const float*)d_in[9];

  char* ws = (char*)d_ws;
  const size_t MD = (size_t)M * D;
  f16* Xh = (f16*)ws;                              // 16 MB (reused as Ch after QKV)
  f16* Wh = (f16*)(ws + (16u << 20));              // 8 MB: Wq,Wk,Wv,Wo f16 (contiguous after Xh)
  f16* Qh = (f16*)(ws + (24u << 20));              // 16 MB
  f16 *KhP, *VhP;
  const size_t need = (24u << 20) + 3 * MD * sizeof(f16);
  if (ws_size >= need) {
    KhP = Qh + MD; VhP = KhP + MD;
  } else {
    KhP = (f16*)d_out; VhP = KhP + MD;
  }
  f16* Ch = Xh;

  cvt_all_kernel<<<dim3(2048), dim3(256), 0, stream>>>(query, Wq, Wk, Wv, Wo, Xh);

  gemm_qkv<<<dim3(8, 64, 3), dim3(256), 0, stream>>>(Xh, Wh, bq, bk, bv, Qh, KhP, VhP);

  attn_kernel<<<dim3(T / 128, NBATCH * H), dim3(256), 0, stream>>>(Qh, KhP, VhP, mask, Ch);

  gemm_out<<<dim3(8, 64), dim3(256), 0, stream>>>(Ch, Wh + 3 * (size_t)D * D, bo, (float*)d_out);
}

// Round 11
// 241.479 us; speedup vs baseline: 1.4919x; 1.3001x over previous
//
#include <hip/hip_runtime.h>

typedef _Float16 f16;
typedef __attribute__((ext_vector_type(8))) _Float16 half8;
typedef __attribute__((ext_vector_type(4))) _Float16 half4;
typedef __attribute__((ext_vector_type(2))) __fp16 fp16x2;
typedef __attribute__((ext_vector_type(4))) float f32x4;
typedef __attribute__((ext_vector_type(16))) float f32x16;

#define DEVINL __device__ __forceinline__

constexpr int NBATCH = 4, T = 2048, D = 1024, H = 16, DH = 64;
constexpr int M = NBATCH * T;                 // 8192 rows
constexpr float SCL2 = 0.18033688011f;        // (1/sqrt(64)) * log2(e), folded into Q at projection

// ---- async global->LDS 16B (linear dest: lds = wavebase + lane*16) ----
DEVINL void async16(const f16* g, f16* l) {
  __builtin_amdgcn_global_load_lds(
      (__attribute__((address_space(1))) void*)(g),
      (__attribute__((address_space(3))) void*)(l), 16, 0, 0);
}

DEVINL unsigned pk2(float x, float y) {
  auto h = __builtin_amdgcn_cvt_pkrtz(x, y);  // __fp16 ext_vector(2)
  return __builtin_bit_cast(unsigned, h);
}

DEVINL fp16x2 u2h(unsigned u) { return __builtin_bit_cast(fp16x2, u); }

union H8U {
  half8 h;
  unsigned u[4];
};

// ---- fused f32 -> f16 convert: query (2M float4) + 4 weights (256K float4 each)
// dst is contiguous: [Xh 8M halfs][Wh 4M halfs]
__global__ void cvt_all_kernel(const float* __restrict__ query,
                               const float* __restrict__ wq, const float* __restrict__ wk,
                               const float* __restrict__ wv, const float* __restrict__ wo,
                               f16* __restrict__ dst) {
  constexpr int NQ4 = M * D / 4;            // 2,097,152
  constexpr int NW4 = D * D / 4;            // 262,144
  constexpr int NT4 = NQ4 + 4 * NW4;
  const float* srcs[4] = {wq, wk, wv, wo};
  int i = blockIdx.x * blockDim.x + threadIdx.x;
  int stride = gridDim.x * blockDim.x;
  for (; i < NT4; i += stride) {
    const float* s;
    int off;
    if (i < NQ4) { s = query; off = i; }
    else {
      int j = i - NQ4;
      s = srcs[j >> 18];          // 2^18 == NW4
      off = j & (NW4 - 1);
    }
    float4 v = reinterpret_cast<const float4*>(s)[off];
    half4 h = {(f16)v.x, (f16)v.y, (f16)v.z, (f16)v.w};
    reinterpret_cast<half4*>(dst)[i] = h;
  }
}

// ---- shared GEMM body: C = (A @ W^T + bias) * oscale (m97 structure, 128x128, BK=32) ----
template<bool F32OUT>
DEVINL void gemm_body(const f16* __restrict__ A, const f16* __restrict__ W,
                      const float* __restrict__ bias, void* __restrict__ out,
                      f16* As, f16* Bs, long bm, long bn, float oscale) {
  constexpr int K = 1024, BK = 32, NCOL = 1024;
  const int tid = threadIdx.x;
  const int lane = tid & 63, wave = tid >> 6;
  const int wr = wave >> 1, wc = wave & 1;
  const int srow = tid >> 2, scol = (tid & 3) * 8;
  const f16* gA = A + (bm + srow) * (long)K + scol;
  const f16* gB = W + (bn + srow) * (long)K + scol;
  f16* lA = &As[srow * BK + scol];
  f16* lB = &Bs[srow * BK + scol];
  const int fr = lane & 15, fk = (lane >> 4) * 8;
  f32x4 acc[4][4] = {};

  for (int k0 = 0; k0 < K; k0 += BK) {
    async16(gA + k0, lA);
    async16(gA + k0 + 64 * K, lA + 64 * BK);
    async16(gB + k0, lB);
    async16(gB + k0 + 64 * K, lB + 64 * BK);
    __syncthreads();
    half8 af[4], bf[4];
#pragma unroll
    for (int m = 0; m < 4; ++m)
      af[m] = *(const half8*)&As[(wr * 64 + m * 16 + fr) * BK + fk];
#pragma unroll
    for (int n = 0; n < 4; ++n)
      bf[n] = *(const half8*)&Bs[(wc * 64 + n * 16 + fr) * BK + fk];
#pragma unroll
    for (int m = 0; m < 4; ++m)
#pragma unroll
      for (int n = 0; n < 4; ++n)
        acc[m][n] = __builtin_amdgcn_mfma_f32_16x16x32_f16(af[m], bf[n], acc[m][n], 0, 0, 0);
    __syncthreads();
  }
  const int rq = (lane >> 4) * 4;
#pragma unroll
  for (int m = 0; m < 4; ++m) {
    const long row = bm + wr * 64 + m * 16 + rq;
#pragma unroll
    for (int n = 0; n < 4; ++n) {
      const long col = bn + wc * 64 + n * 16 + fr;
      const float bb = bias[col];
#pragma unroll
      for (int r = 0; r < 4; ++r) {
        float v = (acc[m][n][r] + bb) * oscale;
        if (F32OUT) ((float*)out)[(row + r) * (long)NCOL + col] = v;
        else        ((f16*)out)[(row + r) * (long)NCOL + col] = (f16)v;
      }
    }
  }
}

// fused QKV: grid (8, 64, 3).  Q output is pre-scaled by SCL2 (softmax scale folded in).
__global__ __launch_bounds__(256) void gemm_qkv(const f16* __restrict__ A,
                                                const f16* __restrict__ Wall,
                                                const float* __restrict__ bq,
                                                const float* __restrict__ bk,
                                                const float* __restrict__ bv,
                                                f16* __restrict__ Qh,
                                                f16* __restrict__ Kh,
                                                f16* __restrict__ Vh) {
  __shared__ __align__(16) f16 As[128 * 32];
  __shared__ __align__(16) f16 Bs[128 * 32];
  const int z = blockIdx.z;
  const f16* W = Wall + (size_t)z * D * D;
  const float* bias = z == 0 ? bq : (z == 1 ? bk : bv);
  f16* out = z == 0 ? Qh : (z == 1 ? Kh : Vh);
  const float oscale = z == 0 ? SCL2 : 1.0f;
  gemm_body<false>(A, W, bias, (void*)out, As, Bs,
                   (long)blockIdx.y * 128, (long)blockIdx.x * 128, oscale);
}

__global__ __launch_bounds__(256) void gemm_out(const f16* __restrict__ A,
                                                const f16* __restrict__ W,
                                                const float* __restrict__ bias,
                                                float* __restrict__ out) {
  __shared__ __align__(16) f16 As[128 * 32];
  __shared__ __align__(16) f16 Bs[128 * 32];
  gemm_body<true>(A, W, bias, (void*)out, As, Bs,
                  (long)blockIdx.y * 128, (long)blockIdx.x * 128, 1.0f);
}

// ---- flash attention, swapped-QK^T 32x32, max-free softmax, 1-iter skew (PV-first) ----
// Body(t): PV(t-1) [consumes pf] -> QK(t) [s in AGPRs] -> exp/pack(t) [rewrites pf].
// The 16 PV+QK MFMAs issue as one cluster; s never lives across an MFMA block on the
// arch-VGPR side (round-9/10 spill fix).  1 barrier/iter; K staged 2 ahead post-barrier
// into the just-read K buffer; V written 1 ahead post-barrier into the just-read V buffer.
__global__ __launch_bounds__(256, 4) void attn_kernel(const f16* __restrict__ Qh,
                                                      const f16* __restrict__ Kh,
                                                      const f16* __restrict__ Vh,
                                                      const int* __restrict__ mask,
                                                      f16* __restrict__ Ch) {
  constexpr int NT = T / 64;
  constexpr int LDV = 72;  // V^T row stride in halfs (144B): measured-cheap LDS pattern
  __shared__ __align__(16) f16 smem[17408];
  f16* Ksb0 = smem;
  f16* Ksb1 = smem + 4096;
  f16* Vtb0 = smem + 8192;
  f16* Vtb1 = smem + 8192 + 4608;

  const int nh = blockIdx.y;
  const int bn = nh >> 4;
  const int bh = nh & 15;
  const int qt0 = blockIdx.x * 128;
  const int tid = threadIdx.x, lane = tid & 63, wave = tid >> 6;
  const int q = lane & 31, hi = lane >> 5;

  const long base = ((long)bn * T) * D + (long)bh * DH;
  const int qrow = qt0 + wave * 32 + q;

  // Q fragments (persistent, pre-scaled): zeroed if this query row is masked
  // (s == 0 -> p == 1 uniform -> O = mean(V), exactly the reference's masked softmax)
  const bool pm = mask[bn * T + qrow] != 0;
  half8 qf[4];
#pragma unroll
  for (int f = 0; f < 4; ++f) {
    qf[f] = *(const half8*)&Qh[base + (long)qrow * D + f * 16 + hi * 8];
    if (!pm) qf[f] = half8{};
  }

  f32x16 o0 = {}, o1 = {};
  float lsum = 0.0f;
  const fp16x2 one2 = {(__fp16)1.0f, (__fp16)1.0f};

  // --- K staging: chunk-XOR swizzled source, linear LDS dest ---
  const int skey = tid >> 3;
  const int sc = tid & 7;
  const int kcol = ((sc ^ (skey & 7)) * 8);
  const f16* ksrc0 = Kh + base + (long)skey * D + kcol;
  const f16* ksrc1 = Kh + base + (long)(skey + 32) * D + kcol;

  // --- V staging: row s = lane, d-cols wave*16 .. +16 ---
  const int vs = lane;
  const int vd = wave * 16;
  const f16* vsrc = Vh + base + (long)vs * D + vd;

  // prologue: K(0)->Ksb0, K(1)->Ksb1 (async); V(0)->Vtb0 via regs; then V(1)->va/vb
  async16(ksrc0, Ksb0 + tid * 8);
  async16(ksrc1, Ksb0 + 2048 + tid * 8);
  async16(ksrc0 + 64 * D, Ksb1 + tid * 8);
  async16(ksrc1 + 64 * D, Ksb1 + 2048 + tid * 8);
  half8 va = *(const half8*)(vsrc);
  half8 vb = *(const half8*)(vsrc + 8);
  {
#pragma unroll
    for (int j = 0; j < 8; ++j) Vtb0[(vd + j) * LDV + vs] = va[j];
#pragma unroll
    for (int j = 0; j < 8; ++j) Vtb0[(vd + 8 + j) * LDV + vs] = vb[j];
  }
  va = *(const half8*)(vsrc + 64 * D);
  vb = *(const half8*)(vsrc + 64 * D + 8);
  __syncthreads();

  half8 pf[4];

  // exp + pack half (S = 16 exp2'd scores -> pf[G0], pf[G0+1]); s-half dies here
#define PACK_HALF(S, G0)                                                        \
  {                                                                             \
    _Pragma("unroll")                                                           \
    for (int r = 0; r < 16; ++r) S[r] = __builtin_amdgcn_exp2f(S[r]);           \
    _Pragma("unroll")                                                           \
    for (int g2 = 0; g2 < 2; ++g2) {                                            \
      const int b = g2 * 8;                                                     \
      unsigned A0 = pk2(S[b + 0], S[b + 1]), A1 = pk2(S[b + 2], S[b + 3]);      \
      unsigned B0 = pk2(S[b + 4], S[b + 5]), B1 = pk2(S[b + 6], S[b + 7]);      \
      float sgs = __builtin_amdgcn_fdot2(u2h(A0), one2, 0.0f, false);           \
      sgs = __builtin_amdgcn_fdot2(u2h(A1), one2, sgs, false);                  \
      sgs = __builtin_amdgcn_fdot2(u2h(B0), one2, sgs, false);                  \
      sgs = __builtin_amdgcn_fdot2(u2h(B1), one2, sgs, false);                  \
      lsum += sgs;                                                              \
      asm("v_permlane32_swap_b32 %0, %1" : "+v"(A0), "+v"(B0));                 \
      asm("v_permlane32_swap_b32 %0, %1" : "+v"(A1), "+v"(B1));                 \
      H8U u;                                                                    \
      u.u[0] = A0; u.u[1] = A1; u.u[2] = B0; u.u[3] = B1;                       \
      pf[(G0) + g2] = u.h;                                                      \
    }                                                                           \
  }

  // post-compute section of iter t: barrier; K(t+2)->KB; V(t+1)->VP; V(t+2)->va/vb
#define POST_SECTION(T_, KB, VP)                                                \
  {                                                                             \
    const int t_ = (T_);                                                        \
    __syncthreads();                                                            \
    if (t_ + 2 < NT) {                                                          \
      const long koff = (long)(t_ + 2) * 64 * D;                                \
      async16(ksrc0 + koff, KB + tid * 8);                                      \
      async16(ksrc1 + koff, KB + 2048 + tid * 8);                               \
    }                                                                           \
    if (t_ + 1 < NT) {                                                          \
      _Pragma("unroll")                                                         \
      for (int j = 0; j < 8; ++j) VP[(vd + j) * LDV + vs] = va[j];              \
      _Pragma("unroll")                                                         \
      for (int j = 0; j < 8; ++j) VP[(vd + 8 + j) * LDV + vs] = vb[j];          \
    }                                                                           \
    if (t_ + 2 < NT) {                                                          \
      const long koff2 = (long)(t_ + 2) * 64 * D;                               \
      va = *(const half8*)(vsrc + koff2);                                       \
      vb = *(const half8*)(vsrc + koff2 + 8);                                   \
    }                                                                           \
  }

  // Body(t), t >= 1: PV(t-1) from VP; QK(t) from KB; exp/pack -> pf; post-section.
#define ATTN_BODY(T_, KB, VP)                                                   \
  {                                                                             \
    f32x16 s0 = {}, s1 = {};                                                    \
    __builtin_amdgcn_s_setprio(1);                                              \
    _Pragma("unroll")                                                           \
    for (int kc = 0; kc < 4; ++kc) {                                            \
      half8 v0f = *(const half8*)&VP[q * LDV + kc * 16 + hi * 8];               \
      half8 v1f = *(const half8*)&VP[(32 + q) * LDV + kc * 16 + hi * 8];        \
      o0 = __builtin_amdgcn_mfma_f32_32x32x16_f16(v0f, pf[kc], o0, 0, 0, 0);    \
      o1 = __builtin_amdgcn_mfma_f32_32x32x16_f16(v1f, pf[kc], o1, 0, 0, 0);    \
    }                                                                           \
    _Pragma("unroll")                                                           \
    for (int f = 0; f < 4; ++f) {                                               \
      const int ck = f * 2 + hi;                                                \
      half8 k0 = *(const half8*)&KB[q * 64 + ((ck ^ (q & 7)) * 8)];             \
      half8 k1 = *(const half8*)&KB[(32 + q) * 64 + ((ck ^ (q & 7)) * 8)];      \
      s0 = __builtin_amdgcn_mfma_f32_32x32x16_f16(k0, qf[f], s0, 0, 0, 0);      \
      s1 = __builtin_amdgcn_mfma_f32_32x32x16_f16(k1, qf[f], s1, 0, 0, 0);      \
    }                                                                           \
    __builtin_amdgcn_s_setprio(0);                                              \
    PACK_HALF(s0, 0)                                                            \
    PACK_HALF(s1, 2)                                                            \
    POST_SECTION(T_, KB, VP)                                                    \
  }

  // ---- prologue iter 0: QK(0) only ----
  {
    f32x16 s0 = {}, s1 = {};
    __builtin_amdgcn_s_setprio(1);
#pragma unroll
    for (int f = 0; f < 4; ++f) {
      const int ck = f * 2 + hi;
      half8 k0 = *(const half8*)&Ksb0[q * 64 + ((ck ^ (q & 7)) * 8)];
      half8 k1 = *(const half8*)&Ksb0[(32 + q) * 64 + ((ck ^ (q & 7)) * 8)];
      s0 = __builtin_amdgcn_mfma_f32_32x32x16_f16(k0, qf[f], s0, 0, 0, 0);
      s1 = __builtin_amdgcn_mfma_f32_32x32x16_f16(k1, qf[f], s1, 0, 0, 0);
    }
    __builtin_amdgcn_s_setprio(0);
    PACK_HALF(s0, 0)
    PACK_HALF(s1, 2)
    POST_SECTION(0, Ksb0, Vtb1)
  }

  // ---- t = 1 .. 30 in parity pairs ----
  for (int t2 = 1; t2 + 1 < NT; t2 += 2) {
    ATTN_BODY(t2, Ksb1, Vtb0)       // t odd:  K in Ksb1, PV(t-1) reads Vtb0
    ATTN_BODY(t2 + 1, Ksb0, Vtb1)   // t even: K in Ksb0, PV(t-1) reads Vtb1
  }
  // ---- t = 31 ----
  ATTN_BODY(NT - 1, Ksb1, Vtb0)
#undef ATTN_BODY
#undef POST_SECTION
#undef PACK_HALF

  // final PV(NT-1): pf from iter NT-1, V(NT-1) in Vtb1 ((NT-1)&1 == 1)
  {
    __builtin_amdgcn_s_setprio(1);
#pragma unroll
    for (int kc = 0; kc < 4; ++kc) {
      half8 v0f = *(const half8*)&Vtb1[q * LDV + kc * 16 + hi * 8];
      half8 v1f = *(const half8*)&Vtb1[(32 + q) * LDV + kc * 16 + hi * 8];
      o0 = __builtin_amdgcn_mfma_f32_32x32x16_f16(v0f, pf[kc], o0, 0, 0, 0);
      o1 = __builtin_amdgcn_mfma_f32_32x32x16_f16(v1f, pf[kc], o1, 0, 0, 0);
    }
    __builtin_amdgcn_s_setprio(0);
  }
  __syncthreads();  // all waves done with K/V LDS before epilogue reuses it

  // ---- epilogue: lrow across hi halves; O/l -> LDS transpose -> coalesced stores ----
  float lrow = lsum + __shfl_xor(lsum, 32);
  constexpr int EPL = 72;
  const float rl = 1.0f / lrow;
  f16* ep = smem + wave * 2304;  // 32 rows x 72 halfs per wave (reuses staging LDS)
#pragma unroll
  for (int r = 0; r < 16; r += 2) {
    const int dd = (r & 3) + 8 * (r >> 2) + 4 * hi;
    *(unsigned*)&ep[q * EPL + dd]      = pk2(o0[r] * rl, o0[r + 1] * rl);
    *(unsigned*)&ep[q * EPL + 32 + dd] = pk2(o1[r] * rl, o1[r + 1] * rl);
  }
  asm volatile("s_waitcnt lgkmcnt(0)" ::: "memory");
  const int rr = lane >> 1, cw = lane & 1;
  const long orow = base + (long)(qt0 + wave * 32 + rr) * D + cw * 32;
#pragma unroll
  for (int c2 = 0; c2 < 4; ++c2) {
    half8 val = *(const half8*)&ep[rr * EPL + cw * 32 + c2 * 8];
    *(half8*)&Ch[orow + c2 * 8] = val;
  }
}

extern "C" void kernel_launch(void* const* d_in, const int* in_sizes, int n_in,
                              void* d_out, int out_size, void* d_ws, size_t ws_size,
                              hipStream_t stream) {
  const float* query = (const float*)d_in[0];
  const int*   mask  = (const int*)d_in[1];
  const float* Wq = (const float*)d_in[2];
  const float* bq = (const float*)d_in[3];
  const float* Wk = (const float*)d_in[4];
  const float* bk = (const float*)d_in[5];
  const float* Wv = (const float*)d_in[6];
  const float* bv = (const float*)d_in[7];
  const float* Wo = (const float*)d_in[8];
  const float* bo = (const float*)d_in[9];

  char* ws = (char*)d_ws;
  const size_t MD = (size_t)M * D;
  f16* Xh = (f16*)ws;                              // 16 MB (reused as Ch after QKV)
  f16* Wh = (f16*)(ws + (16u << 20));              // 8 MB: Wq,Wk,Wv,Wo f16 (contiguous after Xh)
  f16* Qh = (f16*)(ws + (24u << 20));              // 16 MB
  f16 *KhP, *VhP;
  const size_t need = (24u << 20) + 3 * MD * sizeof(f16);
  if (ws_size >= need) {
    KhP = Qh + MD; VhP = KhP + MD;
  } else {
    KhP = (f16*)d_out; VhP = KhP + MD;
  }
  f16* Ch = Xh;

  cvt_all_kernel<<<dim3(2048), dim3(256), 0, stream>>>(query, Wq, Wk, Wv, Wo, Xh);

  gemm_qkv<<<dim3(8, 64, 3), dim3(256), 0, stream>>>(Xh, Wh, bq, bk, bv, Qh, KhP, VhP);

  attn_kernel<<<dim3(T / 128, NBATCH * H), dim3(256), 0, stream>>>(Qh, KhP, VhP, mask, Ch);

  gemm_out<<<dim3(8, 64), dim3(256), 0, stream>>>(Ch, Wh + 3 * (size_t)D * D, bo, (float*)d_out);
}

// Round 12
// 206.212 us; speedup vs baseline: 1.7470x; 1.1710x over previous
//
#include <hip/hip_runtime.h>

typedef _Float16 f16;
typedef __attribute__((ext_vector_type(8))) _Float16 half8;
typedef __attribute__((ext_vector_type(4))) _Float16 half4;
typedef __attribute__((ext_vector_type(2))) __fp16 fp16x2;
typedef __attribute__((ext_vector_type(4))) float f32x4;
typedef __attribute__((ext_vector_type(16))) float f32x16;

#define DEVINL __device__ __forceinline__

constexpr int NBATCH = 4, T = 2048, D = 1024, H = 16, DH = 64;
constexpr int M = NBATCH * T;                 // 8192 rows
constexpr float SCL2 = 0.18033688011f;        // (1/sqrt(64)) * log2(e), folded into Q at projection

// ---- async global->LDS 16B (linear dest: lds = wavebase + lane*16) ----
DEVINL void async16(const f16* g, f16* l) {
  __builtin_amdgcn_global_load_lds(
      (__attribute__((address_space(1))) void*)(g),
      (__attribute__((address_space(3))) void*)(l), 16, 0, 0);
}

DEVINL unsigned pk2(float x, float y) {
  auto h = __builtin_amdgcn_cvt_pkrtz(x, y);  // __fp16 ext_vector(2)
  return __builtin_bit_cast(unsigned, h);
}

DEVINL fp16x2 u2h(unsigned u) { return __builtin_bit_cast(fp16x2, u); }

union H8U {
  half8 h;
  unsigned u[4];
};

// ---- fused f32 -> f16 convert: query (2M float4) + 4 weights (256K float4 each)
// dst is contiguous: [Xh 8M halfs][Wh 4M halfs]
__global__ void cvt_all_kernel(const float* __restrict__ query,
                               const float* __restrict__ wq, const float* __restrict__ wk,
                               const float* __restrict__ wv, const float* __restrict__ wo,
                               f16* __restrict__ dst) {
  constexpr int NQ4 = M * D / 4;            // 2,097,152
  constexpr int NW4 = D * D / 4;            // 262,144
  constexpr int NT4 = NQ4 + 4 * NW4;
  const float* srcs[4] = {wq, wk, wv, wo};
  int i = blockIdx.x * blockDim.x + threadIdx.x;
  int stride = gridDim.x * blockDim.x;
  for (; i < NT4; i += stride) {
    const float* s;
    int off;
    if (i < NQ4) { s = query; off = i; }
    else {
      int j = i - NQ4;
      s = srcs[j >> 18];          // 2^18 == NW4
      off = j & (NW4 - 1);
    }
    float4 v = reinterpret_cast<const float4*>(s)[off];
    half4 h = {(f16)v.x, (f16)v.y, (f16)v.z, (f16)v.w};
    reinterpret_cast<half4*>(dst)[i] = h;
  }
}

// ---- shared GEMM body: C = (A @ W^T + bias) * oscale (m97 structure, 128x128, BK=32) ----
template<bool F32OUT>
DEVINL void gemm_body(const f16* __restrict__ A, const f16* __restrict__ W,
                      const float* __restrict__ bias, void* __restrict__ out,
                      f16* As, f16* Bs, long bm, long bn, float oscale) {
  constexpr int K = 1024, BK = 32, NCOL = 1024;
  const int tid = threadIdx.x;
  const int lane = tid & 63, wave = tid >> 6;
  const int wr = wave >> 1, wc = wave & 1;
  const int srow = tid >> 2, scol = (tid & 3) * 8;
  const f16* gA = A + (bm + srow) * (long)K + scol;
  const f16* gB = W + (bn + srow) * (long)K + scol;
  f16* lA = &As[srow * BK + scol];
  f16* lB = &Bs[srow * BK + scol];
  const int fr = lane & 15, fk = (lane >> 4) * 8;
  f32x4 acc[4][4] = {};

  for (int k0 = 0; k0 < K; k0 += BK) {
    async16(gA + k0, lA);
    async16(gA + k0 + 64 * K, lA + 64 * BK);
    async16(gB + k0, lB);
    async16(gB + k0 + 64 * K, lB + 64 * BK);
    __syncthreads();
    half8 af[4], bf[4];
#pragma unroll
    for (int m = 0; m < 4; ++m)
      af[m] = *(const half8*)&As[(wr * 64 + m * 16 + fr) * BK + fk];
#pragma unroll
    for (int n = 0; n < 4; ++n)
      bf[n] = *(const half8*)&Bs[(wc * 64 + n * 16 + fr) * BK + fk];
#pragma unroll
    for (int m = 0; m < 4; ++m)
#pragma unroll
      for (int n = 0; n < 4; ++n)
        acc[m][n] = __builtin_amdgcn_mfma_f32_16x16x32_f16(af[m], bf[n], acc[m][n], 0, 0, 0);
    __syncthreads();
  }
  const int rq = (lane >> 4) * 4;
#pragma unroll
  for (int m = 0; m < 4; ++m) {
    const long row = bm + wr * 64 + m * 16 + rq;
#pragma unroll
    for (int n = 0; n < 4; ++n) {
      const long col = bn + wc * 64 + n * 16 + fr;
      const float bb = bias[col];
#pragma unroll
      for (int r = 0; r < 4; ++r) {
        float v = (acc[m][n][r] + bb) * oscale;
        if (F32OUT) ((float*)out)[(row + r) * (long)NCOL + col] = v;
        else        ((f16*)out)[(row + r) * (long)NCOL + col] = (f16)v;
      }
    }
  }
}

// fused QKV: grid (8, 64, 3).  Q output is pre-scaled by SCL2 (softmax scale folded in).
__global__ __launch_bounds__(256) void gemm_qkv(const f16* __restrict__ A,
                                                const f16* __restrict__ Wall,
                                                const float* __restrict__ bq,
                                                const float* __restrict__ bk,
                                                const float* __restrict__ bv,
                                                f16* __restrict__ Qh,
                                                f16* __restrict__ Kh,
                                                f16* __restrict__ Vh) {
  __shared__ __align__(16) f16 As[128 * 32];
  __shared__ __align__(16) f16 Bs[128 * 32];
  const int z = blockIdx.z;
  const f16* W = Wall + (size_t)z * D * D;
  const float* bias = z == 0 ? bq : (z == 1 ? bk : bv);
  f16* out = z == 0 ? Qh : (z == 1 ? Kh : Vh);
  const float oscale = z == 0 ? SCL2 : 1.0f;
  gemm_body<false>(A, W, bias, (void*)out, As, Bs,
                   (long)blockIdx.y * 128, (long)blockIdx.x * 128, oscale);
}

__global__ __launch_bounds__(256) void gemm_out(const f16* __restrict__ A,
                                                const f16* __restrict__ W,
                                                const float* __restrict__ bias,
                                                float* __restrict__ out) {
  __shared__ __align__(16) f16 As[128 * 32];
  __shared__ __align__(16) f16 Bs[128 * 32];
  gemm_body<true>(A, W, bias, (void*)out, As, Bs,
                  (long)blockIdx.y * 128, (long)blockIdx.x * 128, 1.0f);
}

// ---- flash attention, swapped-QK^T 32x32, max-free softmax, 1-iter skew (PV-first) ----
// Body(t): PV(t-1) [consumes pf] -> QK(t) -> exp/pack(t) [rewrites pf].
// __launch_bounds__(256,3): 170 VGPR/wave budget -- the skewed live set (~140) fits;
// (256,4)'s 128-reg budget caused the round-9/10/11 scratch spill.  Measured occupancy
// was ~3 blocks/CU anyway, so no occupancy is given up.
__global__ __launch_bounds__(256, 3) void attn_kernel(const f16* __restrict__ Qh,
                                                      const f16* __restrict__ Kh,
                                                      const f16* __restrict__ Vh,
                                                      const int* __restrict__ mask,
                                                      f16* __restrict__ Ch) {
  constexpr int NT = T / 64;
  constexpr int LDV = 72;  // V^T row stride in halfs (144B): measured-cheap LDS pattern
  __shared__ __align__(16) f16 smem[17408];
  f16* Ksb0 = smem;
  f16* Ksb1 = smem + 4096;
  f16* Vtb0 = smem + 8192;
  f16* Vtb1 = smem + 8192 + 4608;

  const int nh = blockIdx.y;
  const int bn = nh >> 4;
  const int bh = nh & 15;
  const int qt0 = blockIdx.x * 128;
  const int tid = threadIdx.x, lane = tid & 63, wave = tid >> 6;
  const int q = lane & 31, hi = lane >> 5;

  const long base = ((long)bn * T) * D + (long)bh * DH;
  const int qrow = qt0 + wave * 32 + q;

  // Q fragments (persistent, pre-scaled): zeroed if this query row is masked
  // (s == 0 -> p == 1 uniform -> O = mean(V), exactly the reference's masked softmax)
  const bool pm = mask[bn * T + qrow] != 0;
  half8 qf[4];
#pragma unroll
  for (int f = 0; f < 4; ++f) {
    qf[f] = *(const half8*)&Qh[base + (long)qrow * D + f * 16 + hi * 8];
    if (!pm) qf[f] = half8{};
  }

  f32x16 o0 = {}, o1 = {};
  float lsum = 0.0f;
  const fp16x2 one2 = {(__fp16)1.0f, (__fp16)1.0f};

  // --- K staging: chunk-XOR swizzled source, linear LDS dest ---
  const int skey = tid >> 3;
  const int sc = tid & 7;
  const int kcol = ((sc ^ (skey & 7)) * 8);
  const f16* ksrc0 = Kh + base + (long)skey * D + kcol;
  const f16* ksrc1 = Kh + base + (long)(skey + 32) * D + kcol;

  // --- V staging: row s = lane, d-cols wave*16 .. +16 ---
  const int vs = lane;
  const int vd = wave * 16;
  const f16* vsrc = Vh + base + (long)vs * D + vd;

  // prologue: K(0)->Ksb0, K(1)->Ksb1 (async); V(0)->Vtb0 via regs; then V(1)->va/vb
  async16(ksrc0, Ksb0 + tid * 8);
  async16(ksrc1, Ksb0 + 2048 + tid * 8);
  async16(ksrc0 + 64 * D, Ksb1 + tid * 8);
  async16(ksrc1 + 64 * D, Ksb1 + 2048 + tid * 8);
  half8 va = *(const half8*)(vsrc);
  half8 vb = *(const half8*)(vsrc + 8);
  {
#pragma unroll
    for (int j = 0; j < 8; ++j) Vtb0[(vd + j) * LDV + vs] = va[j];
#pragma unroll
    for (int j = 0; j < 8; ++j) Vtb0[(vd + 8 + j) * LDV + vs] = vb[j];
  }
  va = *(const half8*)(vsrc + 64 * D);
  vb = *(const half8*)(vsrc + 64 * D + 8);
  __syncthreads();

  half8 pf[4];

  // exp + pack half (S = 16 exp2'd scores -> pf[G0], pf[G0+1]); s-half dies here
#define PACK_HALF(S, G0)                                                        \
  {                                                                             \
    _Pragma("unroll")                                                           \
    for (int r = 0; r < 16; ++r) S[r] = __builtin_amdgcn_exp2f(S[r]);           \
    _Pragma("unroll")                                                           \
    for (int g2 = 0; g2 < 2; ++g2) {                                            \
      const int b = g2 * 8;                                                     \
      unsigned A0 = pk2(S[b + 0], S[b + 1]), A1 = pk2(S[b + 2], S[b + 3]);      \
      unsigned B0 = pk2(S[b + 4], S[b + 5]), B1 = pk2(S[b + 6], S[b + 7]);      \
      float sgs = __builtin_amdgcn_fdot2(u2h(A0), one2, 0.0f, false);           \
      sgs = __builtin_amdgcn_fdot2(u2h(A1), one2, sgs, false);                  \
      sgs = __builtin_amdgcn_fdot2(u2h(B0), one2, sgs, false);                  \
      sgs = __builtin_amdgcn_fdot2(u2h(B1), one2, sgs, false);                  \
      lsum += sgs;                                                              \
      asm("v_permlane32_swap_b32 %0, %1" : "+v"(A0), "+v"(B0));                 \
      asm("v_permlane32_swap_b32 %0, %1" : "+v"(A1), "+v"(B1));                 \
      H8U u;                                                                    \
      u.u[0] = A0; u.u[1] = A1; u.u[2] = B0; u.u[3] = B1;                       \
      pf[(G0) + g2] = u.h;                                                      \
    }                                                                           \
  }

  // post-compute section of iter t: barrier; K(t+2)->KB; V(t+1)->VP; V(t+2)->va/vb
#define POST_SECTION(T_, KB, VP)                                                \
  {                                                                             \
    const int t_ = (T_);                                                        \
    __syncthreads();                                                            \
    if (t_ + 2 < NT) {                                                          \
      const long koff = (long)(t_ + 2) * 64 * D;                                \
      async16(ksrc0 + koff, KB + tid * 8);                                      \
      async16(ksrc1 + koff, KB + 2048 + tid * 8);                               \
    }                                                                           \
    if (t_ + 1 < NT) {                                                          \
      _Pragma("unroll")                                                         \
      for (int j = 0; j < 8; ++j) VP[(vd + j) * LDV + vs] = va[j];              \
      _Pragma("unroll")                                                         \
      for (int j = 0; j < 8; ++j) VP[(vd + 8 + j) * LDV + vs] = vb[j];          \
    }                                                                           \
    if (t_ + 2 < NT) {                                                          \
      const long koff2 = (long)(t_ + 2) * 64 * D;                               \
      va = *(const half8*)(vsrc + koff2);                                       \
      vb = *(const half8*)(vsrc + koff2 + 8);                                   \
    }                                                                           \
  }

  // Body(t), t >= 1: PV(t-1) from VP; QK(t) from KB; exp/pack -> pf; post-section.
#define ATTN_BODY(T_, KB, VP)                                                   \
  {                                                                             \
    f32x16 s0 = {}, s1 = {};                                                    \
    __builtin_amdgcn_s_setprio(1);                                              \
    _Pragma("unroll")                                                           \
    for (int kc = 0; kc < 4; ++kc) {                                            \
      half8 v0f = *(const half8*)&VP[q * LDV + kc * 16 + hi * 8];               \
      half8 v1f = *(const half8*)&VP[(32 + q) * LDV + kc * 16 + hi * 8];        \
      o0 = __builtin_amdgcn_mfma_f32_32x32x16_f16(v0f, pf[kc], o0, 0, 0, 0);    \
      o1 = __builtin_amdgcn_mfma_f32_32x32x16_f16(v1f, pf[kc], o1, 0, 0, 0);    \
    }                                                                           \
    _Pragma("unroll")                                                           \
    for (int f = 0; f < 4; ++f) {                                               \
      const int ck = f * 2 + hi;                                                \
      half8 k0 = *(const half8*)&KB[q * 64 + ((ck ^ (q & 7)) * 8)];             \
      half8 k1 = *(const half8*)&KB[(32 + q) * 64 + ((ck ^ (q & 7)) * 8)];      \
      s0 = __builtin_amdgcn_mfma_f32_32x32x16_f16(k0, qf[f], s0, 0, 0, 0);      \
      s1 = __builtin_amdgcn_mfma_f32_32x32x16_f16(k1, qf[f], s1, 0, 0, 0);      \
    }                                                                           \
    __builtin_amdgcn_s_setprio(0);                                              \
    PACK_HALF(s0, 0)                                                            \
    PACK_HALF(s1, 2)                                                            \
    POST_SECTION(T_, KB, VP)                                                    \
  }

  // ---- prologue iter 0: QK(0) only ----
  {
    f32x16 s0 = {}, s1 = {};
    __builtin_amdgcn_s_setprio(1);
#pragma unroll
    for (int f = 0; f < 4; ++f) {
      const int ck = f * 2 + hi;
      half8 k0 = *(const half8*)&Ksb0[q * 64 + ((ck ^ (q & 7)) * 8)];
      half8 k1 = *(const half8*)&Ksb0[(32 + q) * 64 + ((ck ^ (q & 7)) * 8)];
      s0 = __builtin_amdgcn_mfma_f32_32x32x16_f16(k0, qf[f], s0, 0, 0, 0);
      s1 = __builtin_amdgcn_mfma_f32_32x32x16_f16(k1, qf[f], s1, 0, 0, 0);
    }
    __builtin_amdgcn_s_setprio(0);
    PACK_HALF(s0, 0)
    PACK_HALF(s1, 2)
    POST_SECTION(0, Ksb0, Vtb1)
  }

  // ---- t = 1 .. 30 in parity pairs ----
  for (int t2 = 1; t2 + 1 < NT; t2 += 2) {
    ATTN_BODY(t2, Ksb1, Vtb0)       // t odd:  K in Ksb1, PV(t-1) reads Vtb0
    ATTN_BODY(t2 + 1, Ksb0, Vtb1)   // t even: K in Ksb0, PV(t-1) reads Vtb1
  }
  // ---- t = 31 ----
  ATTN_BODY(NT - 1, Ksb1, Vtb0)
#undef ATTN_BODY
#undef POST_SECTION
#undef PACK_HALF

  // final PV(NT-1): pf from iter NT-1, V(NT-1) in Vtb1 ((NT-1)&1 == 1)
  {
    __builtin_amdgcn_s_setprio(1);
#pragma unroll
    for (int kc = 0; kc < 4; ++kc) {
      half8 v0f = *(const half8*)&Vtb1[q * LDV + kc * 16 + hi * 8];
      half8 v1f = *(const half8*)&Vtb1[(32 + q) * LDV + kc * 16 + hi * 8];
      o0 = __builtin_amdgcn_mfma_f32_32x32x16_f16(v0f, pf[kc], o0, 0, 0, 0);
      o1 = __builtin_amdgcn_mfma_f32_32x32x16_f16(v1f, pf[kc], o1, 0, 0, 0);
    }
    __builtin_amdgcn_s_setprio(0);
  }
  __syncthreads();  // all waves done with K/V LDS before epilogue reuses it

  // ---- epilogue: lrow across hi halves; O/l -> LDS transpose -> coalesced stores ----
  float lrow = lsum + __shfl_xor(lsum, 32);
  constexpr int EPL = 72;
  const float rl = 1.0f / lrow;
  f16* ep = smem + wave * 2304;  // 32 rows x 72 halfs per wave (reuses staging LDS)
#pragma unroll
  for (int r = 0; r < 16; r += 2) {
    const int dd = (r & 3) + 8 * (r >> 2) + 4 * hi;
    *(unsigned*)&ep[q * EPL + dd]      = pk2(o0[r] * rl, o0[r + 1] * rl);
    *(unsigned*)&ep[q * EPL + 32 + dd] = pk2(o1[r] * rl, o1[r + 1] * rl);
  }
  asm volatile("s_waitcnt lgkmcnt(0)" ::: "memory");
  const int rr = lane >> 1, cw = lane & 1;
  const long orow = base + (long)(qt0 + wave * 32 + rr) * D + cw * 32;
#pragma unroll
  for (int c2 = 0; c2 < 4; ++c2) {
    half8 val = *(const half8*)&ep[rr * EPL + cw * 32 + c2 * 8];
    *(half8*)&Ch[orow + c2 * 8] = val;
  }
}

extern "C" void kernel_launch(void* const* d_in, const int* in_sizes, int n_in,
                              void* d_out, int out_size, void* d_ws, size_t ws_size,
                              hipStream_t stream) {
  const float* query = (const float*)d_in[0];
  const int*   mask  = (const int*)d_in[1];
  const float* Wq = (const float*)d_in[2];
  const float* bq = (const float*)d_in[3];
  const float* Wk = (const float*)d_in[4];
  const float* bk = (const float*)d_in[5];
  const float* Wv = (const float*)d_in[6];
  const float* bv = (const float*)d_in[7];
  const float* Wo = (const float*)d_in[8];
  const float* bo = (const float*)d_in[9];

  char* ws = (char*)d_ws;
  const size_t MD = (size_t)M * D;
  f16* Xh = (f16*)ws;                              // 16 MB (reused as Ch after QKV)
  f16* Wh = (f16*)(ws + (16u << 20));              // 8 MB: Wq,Wk,Wv,Wo f16 (contiguous after Xh)
  f16* Qh = (f16*)(ws + (24u << 20));              // 16 MB
  f16 *KhP, *VhP;
  const size_t need = (24u << 20) + 3 * MD * sizeof(f16);
  if (ws_size >= need) {
    KhP = Qh + MD; VhP = KhP + MD;
  } else {
    KhP = (f16*)d_out; VhP = KhP + MD;
  }
  f16* Ch = Xh;

  cvt_all_kernel<<<dim3(2048), dim3(256), 0, stream>>>(query, Wq, Wk, Wv, Wo, Xh);

  gemm_qkv<<<dim3(8, 64, 3), dim3(256), 0, stream>>>(Xh, Wh, bq, bk, bv, Qh, KhP, VhP);

  attn_kernel<<<dim3(T / 128, NBATCH * H), dim3(256), 0, stream>>>(Qh, KhP, VhP, mask, Ch);

  gemm_out<<<dim3(8, 64), dim3(256), 0, stream>>>(Ch, Wh + 3 * (size_t)D * D, bo, (float*)d_out);
}